// Round 10
// baseline (248.071 us; speedup 1.0000x reference)
//
#include <hip/hip_runtime.h>
#include <hip/hip_bf16.h>

// MultiHeadAttention B=2,S=2048,D=1024,H=16,Dh=64. fp32 I/O, bf16 MFMA compute.
// R10 = R9 with gemm_out A-staging fixed: ONE cp16 per wave at wofs tiles the
// whole 64x32 A panel (lane identity (l>>2)*32+(l&3)*8 == l*8). R9 had waves
// 2/3 writing wofs-1024 -> raced waves 0/1 and left rows 32..63 stale.
// Single-barrier dbuf K-loops everywhere; attn register-prefetch + dbuf.

typedef short bf16x8 __attribute__((ext_vector_type(8)));
typedef short bf16x4 __attribute__((ext_vector_type(4)));
typedef float f32x4  __attribute__((ext_vector_type(4)));

constexpr size_t NE = (size_t)4096 * 1024;   // elems of [B*S, D]
constexpr size_t NW = (size_t)1024 * 1024;   // elems of [D, D]

#if __has_builtin(__builtin_amdgcn_exp2f)
#define EXP2(x) __builtin_amdgcn_exp2f(x)
#else
#define EXP2(x) exp2f(x)
#endif

__device__ __forceinline__ short f2bf(float f) {
  __hip_bfloat16 h = __float2bfloat16(f);
  return *reinterpret_cast<short*>(&h);
}

__device__ __forceinline__ void cp16(const short* g, short* l) {
  __builtin_amdgcn_global_load_lds(
      (const __attribute__((address_space(1))) void*)g,
      (__attribute__((address_space(3))) void*)l, 16, 0, 0);
}

// ---------------- fused fp32 -> bf16 conversion, 16 slices of 1M elems
__global__ __launch_bounds__(256) void cvt_kernel(
    const float* q, const float* k, const float* v,
    const float* Wq, const float* Wk, const float* Wv, const float* Wo,
    short* qb, short* kb, short* vb,
    short* Wqb, short* Wkb, short* Wvb, short* Wob) {
  const int y = blockIdx.y;
  const float* s; short* d;
  if (y < 12) {
    const int t = y >> 2;
    const size_t off = (size_t)(y & 3) << 20;
    s = (t == 0 ? q : (t == 1 ? k : v)) + off;
    d = (t == 0 ? qb : (t == 1 ? kb : vb)) + off;
  } else {
    s = (y == 12 ? Wq : (y == 13 ? Wk : (y == 14 ? Wv : Wo)));
    d = (y == 12 ? Wqb : (y == 13 ? Wkb : (y == 14 ? Wvb : Wob)));
  }
  size_t i = (size_t)blockIdx.x * 256 + threadIdx.x;
  float4 val = ((const float4*)s)[i];
  bf16x4 o;
  o[0] = f2bf(val.x); o[1] = f2bf(val.y); o[2] = f2bf(val.z); o[3] = f2bf(val.w);
  ((bf16x4*)d)[i] = o;
}

// ---------------- fused Q/K/V projection GEMM: C = (A @ W^T + b) * scale
// 128x128 tile, BK=32, dbuf + single barrier per round (32 rounds).
__global__ __launch_bounds__(256) void gemm_qkv(
    const short* __restrict__ A0, const short* __restrict__ A1, const short* __restrict__ A2,
    const short* __restrict__ W0, const short* __restrict__ W1, const short* __restrict__ W2,
    const float* __restrict__ b0, const float* __restrict__ b1, const float* __restrict__ b2,
    short* __restrict__ C0, short* __restrict__ C1, short* __restrict__ Cv) {
  __shared__ short As[2][128 * 32];
  __shared__ short Bs[2][128 * 32];
  const int which = blockIdx.y;
  const short* A    = which == 0 ? A0 : (which == 1 ? A1 : A2);
  const short* W    = which == 0 ? W0 : (which == 1 ? W1 : W2);
  const float* bias = which == 0 ? b0 : (which == 1 ? b1 : b2);
  const float scale = which == 0 ? 0.18033688011112042f : 1.0f;  // 0.125*log2e

  const int tid  = threadIdx.x;
  const int bm   = (int)blockIdx.x >> 3;
  const int bn   = (int)blockIdx.x & 7;
  const int lane = tid & 63, wid = tid >> 6;
  const int g = lane >> 4, l15 = lane & 15;
  const int wm = (wid >> 1) * 64, wn = (wid & 1) * 64;

  const short* Ag = A + (size_t)(bm * 128 + (tid >> 2)) * 1024 + (tid & 3) * 8;
  const short* Wg = W + (size_t)(bn * 128 + (tid >> 2)) * 1024 + (tid & 3) * 8;
  const int wofs = wid * 512;

  f32x4 acc[4][4];
#pragma unroll
  for (int i = 0; i < 4; ++i)
#pragma unroll
    for (int j = 0; j < 4; ++j) acc[i][j] = (f32x4){0.f, 0.f, 0.f, 0.f};

  // stage round 0 into buf 0
  cp16(Ag,             As[0] + wofs);
  cp16(Ag + 64 * 1024, As[0] + wofs + 2048);
  cp16(Wg,             Bs[0] + wofs);
  cp16(Wg + 64 * 1024, Bs[0] + wofs + 2048);

  for (int r = 0; r < 32; ++r) {
    const int cur = r & 1;
    __syncthreads();   // drains DMA issued a full round ago; separates buffers
    if (r < 31) {
      const int kk = (r + 1) * 32, nxt = cur ^ 1;
      cp16(Ag + kk,             As[nxt] + wofs);
      cp16(Ag + 64 * 1024 + kk, As[nxt] + wofs + 2048);
      cp16(Wg + kk,             Bs[nxt] + wofs);
      cp16(Wg + 64 * 1024 + kk, Bs[nxt] + wofs + 2048);
    }
    bf16x8 af[4], bf[4];
#pragma unroll
    for (int mt = 0; mt < 4; ++mt)
      af[mt] = *(const bf16x8*)&As[cur][(wm + mt * 16 + l15) * 32 + g * 8];
#pragma unroll
    for (int nt = 0; nt < 4; ++nt)
      bf[nt] = *(const bf16x8*)&Bs[cur][(wn + nt * 16 + l15) * 32 + g * 8];
#pragma unroll
    for (int mt = 0; mt < 4; ++mt)
#pragma unroll
      for (int nt = 0; nt < 4; ++nt)
        acc[mt][nt] = __builtin_amdgcn_mfma_f32_16x16x32_bf16(
            af[mt], bf[nt], acc[mt][nt], 0, 0, 0);
  }

  const int col0 = bn * 128 + wn;
  if (which < 2) {
    short* C = which == 0 ? C0 : C1;
#pragma unroll
    for (int nt = 0; nt < 4; ++nt) {
      const int col = col0 + nt * 16 + l15;
      const float bb = bias[col];
#pragma unroll
      for (int mt = 0; mt < 4; ++mt) {
        const int m0 = bm * 128 + wm + mt * 16 + g * 4;
#pragma unroll
        for (int r = 0; r < 4; ++r)
          C[(size_t)(m0 + r) * 1024 + col] = f2bf((acc[mt][nt][r] + bb) * scale);
      }
    }
  } else {
    // V: write transposed per head [b,h,dh,s]
#pragma unroll
    for (int nt = 0; nt < 4; ++nt) {
      const int col = col0 + nt * 16 + l15;
      const int h = col >> 6, dh = col & 63;
      const float bb = bias[col];
#pragma unroll
      for (int mt = 0; mt < 4; ++mt) {
        const int m0 = bm * 128 + wm + mt * 16 + g * 4;   // 4-aligned, same b
        const int bb_ = m0 >> 11, s0 = m0 & 2047;
        bf16x4 o;
#pragma unroll
        for (int r = 0; r < 4; ++r) o[r] = f2bf(acc[mt][nt][r] + bb);
        *(bf16x4*)&Cv[(((size_t)bb_ * 16 + h) * 64 + dh) * 2048 + s0] = o;
      }
    }
  }
}

// ---------------- output projection: fp32 out = A(bf16) @ W^T + b
// 64x128 tile (512 blocks, 2/CU), dbuf + single barrier per round.
__global__ __launch_bounds__(256) void gemm_out(
    const short* __restrict__ A, const short* __restrict__ W,
    const float* __restrict__ bias, float* __restrict__ C) {
  __shared__ short As[2][64 * 32];
  __shared__ short Bs[2][128 * 32];
  const int tid  = threadIdx.x;
  const int bm   = (int)blockIdx.x >> 3;    // 64 M-tiles
  const int bn   = (int)blockIdx.x & 7;     // 8 N-tiles
  const int lane = tid & 63, wid = tid >> 6;
  const int g = lane >> 4, l15 = lane & 15;
  const int wm = (wid >> 1) * 32, wn = (wid & 1) * 64;

  const short* Ag = A + (size_t)(bm * 64 + (tid >> 2)) * 1024 + (tid & 3) * 8;
  const short* Wg = W + (size_t)(bn * 128 + (tid >> 2)) * 1024 + (tid & 3) * 8;
  const int wofs = wid * 512;

  f32x4 acc[2][4];
#pragma unroll
  for (int i = 0; i < 2; ++i)
#pragma unroll
    for (int j = 0; j < 4; ++j) acc[i][j] = (f32x4){0.f, 0.f, 0.f, 0.f};

  // A panel (64x32 = 2048 shorts): ONE cp16 per wave at wofs tiles it exactly
  // (R8-proven). B panel (128x32): two cp16 per wave.
  cp16(Ag,             As[0] + wofs);
  cp16(Wg,             Bs[0] + wofs);
  cp16(Wg + 64 * 1024, Bs[0] + wofs + 2048);

  for (int r = 0; r < 32; ++r) {
    const int cur = r & 1;
    __syncthreads();
    if (r < 31) {
      const int kk = (r + 1) * 32, nxt = cur ^ 1;
      cp16(Ag + kk,             As[nxt] + wofs);
      cp16(Wg + kk,             Bs[nxt] + wofs);
      cp16(Wg + 64 * 1024 + kk, Bs[nxt] + wofs + 2048);
    }
    bf16x8 af[2], bf[4];
#pragma unroll
    for (int mt = 0; mt < 2; ++mt)
      af[mt] = *(const bf16x8*)&As[cur][(wm + mt * 16 + l15) * 32 + g * 8];
#pragma unroll
    for (int nt = 0; nt < 4; ++nt)
      bf[nt] = *(const bf16x8*)&Bs[cur][(wn + nt * 16 + l15) * 32 + g * 8];
#pragma unroll
    for (int mt = 0; mt < 2; ++mt)
#pragma unroll
      for (int nt = 0; nt < 4; ++nt)
        acc[mt][nt] = __builtin_amdgcn_mfma_f32_16x16x32_bf16(
            af[mt], bf[nt], acc[mt][nt], 0, 0, 0);
  }

  const int col0 = bn * 128 + wn;
#pragma unroll
  for (int nt = 0; nt < 4; ++nt) {
    const int col = col0 + nt * 16 + l15;
    const float bb = bias[col];
#pragma unroll
    for (int mt = 0; mt < 2; ++mt) {
      const int m0 = bm * 64 + wm + mt * 16 + g * 4;
#pragma unroll
      for (int r = 0; r < 4; ++r)
        C[(size_t)(m0 + r) * 1024 + col] = acc[mt][nt][r] + bb;
    }
  }
}

// ---------------- flash attention, static-max exp2 softmax, full keys.
// Register prefetch + double-buffered K/V LDS -> ONE barrier per 64-key tile.
__global__ __launch_bounds__(256) void attn_kernel(
    const short* __restrict__ Q, const short* __restrict__ K,
    const short* __restrict__ Vg, short* __restrict__ O) {
  __shared__ short Kt[2][64][72];   // [buf][key][dh]
  __shared__ short Vt[2][64][72];   // [buf][dh][key]
  __shared__ short Pt[4][32][72];   // per-wave [qrow][key]

  const int tid  = threadIdx.x;
  const int qt   = (int)blockIdx.x & 15;    // 16 q-tiles
  const int bh   = (int)blockIdx.x >> 4;    // 32 (b,h)
  const int b    = bh >> 4, h = bh & 15;
  const int lane = tid & 63, wid = tid >> 6;
  const int g = lane >> 4, l15 = lane & 15;

  const int q0 = qt * 128 + wid * 32;
  bf16x8 qf[2][2];
#pragma unroll
  for (int mt = 0; mt < 2; ++mt) {
    const size_t base = (size_t)(b * 2048 + q0 + mt * 16 + l15) * 1024 + h * 64;
    qf[mt][0] = *(const bf16x8*)(Q + base + g * 8);
    qf[mt][1] = *(const bf16x8*)(Q + base + 32 + g * 8);
  }

  f32x4 o_acc[2][4];
#pragma unroll
  for (int i = 0; i < 2; ++i)
#pragma unroll
    for (int j = 0; j < 4; ++j) o_acc[i][j] = (f32x4){0.f, 0.f, 0.f, 0.f};
  float l_i[2][4];
#pragma unroll
  for (int i = 0; i < 2; ++i)
#pragma unroll
    for (int r = 0; r < 4; ++r) l_i[i][r] = 0.f;

  const int srow = tid >> 2, sch = tid & 3;
  const short* Kbase = K + (size_t)(b * 2048) * 1024 + h * 64 + sch * 8;
  const short* Vbase = Vg + (size_t)((b * 16 + h) * 64 + srow) * 2048 + sch * 8;

  // prefetch tile 0 into registers
  bf16x8 nk0, nk1, nv0, nv1;
  {
    const short* krow = Kbase + (size_t)srow * 1024;
    nk0 = *(const bf16x8*)(krow);
    nk1 = *(const bf16x8*)(krow + 32);
    nv0 = *(const bf16x8*)(Vbase);
    nv1 = *(const bf16x8*)(Vbase + 32);
  }

  for (int kt = 0; kt < 32; ++kt) {
    const int cur = kt & 1;
    // store prefetched tile into current buffer
    *(bf16x8*)&Kt[cur][srow][sch * 8]      = nk0;
    *(bf16x8*)&Kt[cur][srow][sch * 8 + 32] = nk1;
    *(bf16x8*)&Vt[cur][srow][sch * 8]      = nv0;
    *(bf16x8*)&Vt[cur][srow][sch * 8 + 32] = nv1;
    __syncthreads();   // ONE barrier: stores visible; prev-buf reads all done

    // issue next tile's global loads; they land during this tile's compute
    if (kt < 31) {
      const short* krow = Kbase + (size_t)((kt + 1) * 64 + srow) * 1024;
      nk0 = *(const bf16x8*)(krow);
      nk1 = *(const bf16x8*)(krow + 32);
      nv0 = *(const bf16x8*)(Vbase + (kt + 1) * 64);
      nv1 = *(const bf16x8*)(Vbase + (kt + 1) * 64 + 32);
    }

    // S = Q K^T (exp2 domain): col=key(l15), row=q(g*4+r)
    f32x4 sv[2][4];
#pragma unroll
    for (int nt = 0; nt < 4; ++nt) {
      bf16x8 kf0 = *(const bf16x8*)&Kt[cur][nt * 16 + l15][g * 8];
      bf16x8 kf1 = *(const bf16x8*)&Kt[cur][nt * 16 + l15][32 + g * 8];
#pragma unroll
      for (int mt = 0; mt < 2; ++mt) {
        f32x4 z = (f32x4){0.f, 0.f, 0.f, 0.f};
        z = __builtin_amdgcn_mfma_f32_16x16x32_bf16(qf[mt][0], kf0, z, 0, 0, 0);
        z = __builtin_amdgcn_mfma_f32_16x16x32_bf16(qf[mt][1], kf1, z, 0, 0, 0);
        sv[mt][nt] = z;
      }
    }

    // static-max softmax: p = exp2(s), lane-local l accumulation, P -> LDS
#pragma unroll
    for (int mt = 0; mt < 2; ++mt)
#pragma unroll
      for (int r = 0; r < 4; ++r) {
        float p0 = EXP2(sv[mt][0][r]);
        float p1 = EXP2(sv[mt][1][r]);
        float p2 = EXP2(sv[mt][2][r]);
        float p3 = EXP2(sv[mt][3][r]);
        l_i[mt][r] += (p0 + p1) + (p2 + p3);
        const int pr = mt * 16 + g * 4 + r;
        Pt[wid][pr][l15]      = f2bf(p0);
        Pt[wid][pr][16 + l15] = f2bf(p1);
        Pt[wid][pr][32 + l15] = f2bf(p2);
        Pt[wid][pr][48 + l15] = f2bf(p3);
      }
    // no barrier: Pt slab is wave-private; per-wave DS ops execute in order

    bf16x8 pf[2][2];
#pragma unroll
    for (int mt = 0; mt < 2; ++mt) {
      pf[mt][0] = *(const bf16x8*)&Pt[wid][mt * 16 + l15][g * 8];
      pf[mt][1] = *(const bf16x8*)&Pt[wid][mt * 16 + l15][32 + g * 8];
    }
#pragma unroll
    for (int nt = 0; nt < 4; ++nt) {
      bf16x8 vf0 = *(const bf16x8*)&Vt[cur][nt * 16 + l15][g * 8];
      bf16x8 vf1 = *(const bf16x8*)&Vt[cur][nt * 16 + l15][32 + g * 8];
#pragma unroll
      for (int mt = 0; mt < 2; ++mt) {
        o_acc[mt][nt] = __builtin_amdgcn_mfma_f32_16x16x32_bf16(
            pf[mt][0], vf0, o_acc[mt][nt], 0, 0, 0);
        o_acc[mt][nt] = __builtin_amdgcn_mfma_f32_16x16x32_bf16(
            pf[mt][1], vf1, o_acc[mt][nt], 0, 0, 0);
      }
    }
  }

  // epilogue: reduce l across 16 lanes, normalize, store bf16
#pragma unroll
  for (int mt = 0; mt < 2; ++mt)
#pragma unroll
    for (int r = 0; r < 4; ++r) {
      float l = l_i[mt][r];
#pragma unroll
      for (int off = 1; off < 16; off <<= 1) l += __shfl_xor(l, off, 64);
      const float inv = 1.0f / l;
      const int row = q0 + mt * 16 + g * 4 + r;
      const size_t base = (size_t)(b * 2048 + row) * 1024 + h * 64;
#pragma unroll
      for (int nt = 0; nt < 4; ++nt)
        O[base + nt * 16 + l15] = f2bf(o_acc[mt][nt][r] * inv);
    }
}

extern "C" void kernel_launch(void* const* d_in, const int* in_sizes, int n_in,
                              void* d_out, int out_size, void* d_ws, size_t ws_size,
                              hipStream_t stream) {
  (void)in_sizes; (void)n_in; (void)out_size; (void)ws_size;
  const float* q  = (const float*)d_in[0];
  const float* k  = (const float*)d_in[1];
  const float* v  = (const float*)d_in[2];
  const float* Wq = (const float*)d_in[3];
  const float* bq = (const float*)d_in[4];
  const float* Wk = (const float*)d_in[5];
  const float* bk = (const float*)d_in[6];
  const float* Wv = (const float*)d_in[7];
  const float* bv = (const float*)d_in[8];
  const float* Wo = (const float*)d_in[9];
  const float* bo = (const float*)d_in[10];
  float* out = (float*)d_out;

  short* qb  = (short*)d_ws;       // bf16 inputs
  short* kb  = qb + NE;
  short* vb  = kb + NE;
  short* Wqb = vb + NE;            // bf16 weights
  short* Wkb = Wqb + NW;
  short* Wvb = Wkb + NW;
  short* Wob = Wvb + NW;
  short* Qw  = Wob + NW;           // projected Q (pre-scaled)
  short* Kw  = Qw + NE;
  short* Vtg = Kw + NE;            // projected V [b,h,dh,s]
  short* Ob  = qb;                 // attention out (qb dead after gemm_qkv)

  cvt_kernel<<<dim3(1024, 16), 256, 0, stream>>>(q, k, v, Wq, Wk, Wv, Wo,
                                                 qb, kb, vb, Wqb, Wkb, Wvb, Wob);
  gemm_qkv<<<dim3(256, 3), 256, 0, stream>>>(qb, kb, vb, Wqb, Wkb, Wvb,
                                             bq, bk, bv, Qw, Kw, Vtg);
  attn_kernel<<<512, 256, 0, stream>>>(Qw, Kw, Vtg, Ob);
  gemm_out<<<512, 256, 0, stream>>>(Ob, Wob, bo, out);
}

// Round 11
// 245.136 us; speedup vs baseline: 1.0120x; 1.0120x over previous
//
#include <hip/hip_runtime.h>
#include <hip/hip_bf16.h>

// MultiHeadAttention B=2,S=2048,D=1024,H=16,Dh=64. fp32 I/O, bf16 MFMA compute.
// R11: attn reworked for LDS arithmetic intensity -- 64 q-rows per wave
// (Q-tile 256/block, grid 256). kf/vf fragment reads amortized over 4 m-tiles:
// LDS cyc per q-row drops 1.33x, MFMA:LDS ratio doubles. GEMMs = R10 (dbuf
// proven neutral, kept).

typedef short bf16x8 __attribute__((ext_vector_type(8)));
typedef short bf16x4 __attribute__((ext_vector_type(4)));
typedef float f32x4  __attribute__((ext_vector_type(4)));

constexpr size_t NE = (size_t)4096 * 1024;   // elems of [B*S, D]
constexpr size_t NW = (size_t)1024 * 1024;   // elems of [D, D]

#if __has_builtin(__builtin_amdgcn_exp2f)
#define EXP2(x) __builtin_amdgcn_exp2f(x)
#else
#define EXP2(x) exp2f(x)
#endif

__device__ __forceinline__ short f2bf(float f) {
  __hip_bfloat16 h = __float2bfloat16(f);
  return *reinterpret_cast<short*>(&h);
}

__device__ __forceinline__ void cp16(const short* g, short* l) {
  __builtin_amdgcn_global_load_lds(
      (const __attribute__((address_space(1))) void*)g,
      (__attribute__((address_space(3))) void*)l, 16, 0, 0);
}

// ---------------- fused fp32 -> bf16 conversion, 16 slices of 1M elems
__global__ __launch_bounds__(256) void cvt_kernel(
    const float* q, const float* k, const float* v,
    const float* Wq, const float* Wk, const float* Wv, const float* Wo,
    short* qb, short* kb, short* vb,
    short* Wqb, short* Wkb, short* Wvb, short* Wob) {
  const int y = blockIdx.y;
  const float* s; short* d;
  if (y < 12) {
    const int t = y >> 2;
    const size_t off = (size_t)(y & 3) << 20;
    s = (t == 0 ? q : (t == 1 ? k : v)) + off;
    d = (t == 0 ? qb : (t == 1 ? kb : vb)) + off;
  } else {
    s = (y == 12 ? Wq : (y == 13 ? Wk : (y == 14 ? Wv : Wo)));
    d = (y == 12 ? Wqb : (y == 13 ? Wkb : (y == 14 ? Wvb : Wob)));
  }
  size_t i = (size_t)blockIdx.x * 256 + threadIdx.x;
  float4 val = ((const float4*)s)[i];
  bf16x4 o;
  o[0] = f2bf(val.x); o[1] = f2bf(val.y); o[2] = f2bf(val.z); o[3] = f2bf(val.w);
  ((bf16x4*)d)[i] = o;
}

// ---------------- fused Q/K/V projection GEMM: C = (A @ W^T + b) * scale
// 128x128 tile, BK=32, dbuf + single barrier per round (32 rounds).
__global__ __launch_bounds__(256) void gemm_qkv(
    const short* __restrict__ A0, const short* __restrict__ A1, const short* __restrict__ A2,
    const short* __restrict__ W0, const short* __restrict__ W1, const short* __restrict__ W2,
    const float* __restrict__ b0, const float* __restrict__ b1, const float* __restrict__ b2,
    short* __restrict__ C0, short* __restrict__ C1, short* __restrict__ Cv) {
  __shared__ short As[2][128 * 32];
  __shared__ short Bs[2][128 * 32];
  const int which = blockIdx.y;
  const short* A    = which == 0 ? A0 : (which == 1 ? A1 : A2);
  const short* W    = which == 0 ? W0 : (which == 1 ? W1 : W2);
  const float* bias = which == 0 ? b0 : (which == 1 ? b1 : b2);
  const float scale = which == 0 ? 0.18033688011112042f : 1.0f;  // 0.125*log2e

  const int tid  = threadIdx.x;
  const int bm   = (int)blockIdx.x >> 3;
  const int bn   = (int)blockIdx.x & 7;
  const int lane = tid & 63, wid = tid >> 6;
  const int g = lane >> 4, l15 = lane & 15;
  const int wm = (wid >> 1) * 64, wn = (wid & 1) * 64;

  const short* Ag = A + (size_t)(bm * 128 + (tid >> 2)) * 1024 + (tid & 3) * 8;
  const short* Wg = W + (size_t)(bn * 128 + (tid >> 2)) * 1024 + (tid & 3) * 8;
  const int wofs = wid * 512;

  f32x4 acc[4][4];
#pragma unroll
  for (int i = 0; i < 4; ++i)
#pragma unroll
    for (int j = 0; j < 4; ++j) acc[i][j] = (f32x4){0.f, 0.f, 0.f, 0.f};

  cp16(Ag,             As[0] + wofs);
  cp16(Ag + 64 * 1024, As[0] + wofs + 2048);
  cp16(Wg,             Bs[0] + wofs);
  cp16(Wg + 64 * 1024, Bs[0] + wofs + 2048);

  for (int r = 0; r < 32; ++r) {
    const int cur = r & 1;
    __syncthreads();
    if (r < 31) {
      const int kk = (r + 1) * 32, nxt = cur ^ 1;
      cp16(Ag + kk,             As[nxt] + wofs);
      cp16(Ag + 64 * 1024 + kk, As[nxt] + wofs + 2048);
      cp16(Wg + kk,             Bs[nxt] + wofs);
      cp16(Wg + 64 * 1024 + kk, Bs[nxt] + wofs + 2048);
    }
    bf16x8 af[4], bf[4];
#pragma unroll
    for (int mt = 0; mt < 4; ++mt)
      af[mt] = *(const bf16x8*)&As[cur][(wm + mt * 16 + l15) * 32 + g * 8];
#pragma unroll
    for (int nt = 0; nt < 4; ++nt)
      bf[nt] = *(const bf16x8*)&Bs[cur][(wn + nt * 16 + l15) * 32 + g * 8];
#pragma unroll
    for (int mt = 0; mt < 4; ++mt)
#pragma unroll
      for (int nt = 0; nt < 4; ++nt)
        acc[mt][nt] = __builtin_amdgcn_mfma_f32_16x16x32_bf16(
            af[mt], bf[nt], acc[mt][nt], 0, 0, 0);
  }

  const int col0 = bn * 128 + wn;
  if (which < 2) {
    short* C = which == 0 ? C0 : C1;
#pragma unroll
    for (int nt = 0; nt < 4; ++nt) {
      const int col = col0 + nt * 16 + l15;
      const float bb = bias[col];
#pragma unroll
      for (int mt = 0; mt < 4; ++mt) {
        const int m0 = bm * 128 + wm + mt * 16 + g * 4;
#pragma unroll
        for (int r = 0; r < 4; ++r)
          C[(size_t)(m0 + r) * 1024 + col] = f2bf((acc[mt][nt][r] + bb) * scale);
      }
    }
  } else {
    // V: write transposed per head [b,h,dh,s]
#pragma unroll
    for (int nt = 0; nt < 4; ++nt) {
      const int col = col0 + nt * 16 + l15;
      const int h = col >> 6, dh = col & 63;
      const float bb = bias[col];
#pragma unroll
      for (int mt = 0; mt < 4; ++mt) {
        const int m0 = bm * 128 + wm + mt * 16 + g * 4;   // 4-aligned, same b
        const int bb_ = m0 >> 11, s0 = m0 & 2047;
        bf16x4 o;
#pragma unroll
        for (int r = 0; r < 4; ++r) o[r] = f2bf(acc[mt][nt][r] + bb);
        *(bf16x4*)&Cv[(((size_t)bb_ * 16 + h) * 64 + dh) * 2048 + s0] = o;
      }
    }
  }
}

// ---------------- output projection: fp32 out = A(bf16) @ W^T + b
// 64x128 tile (512 blocks, 2/CU), dbuf + single barrier per round.
__global__ __launch_bounds__(256) void gemm_out(
    const short* __restrict__ A, const short* __restrict__ W,
    const float* __restrict__ bias, float* __restrict__ C) {
  __shared__ short As[2][64 * 32];
  __shared__ short Bs[2][128 * 32];
  const int tid  = threadIdx.x;
  const int bm   = (int)blockIdx.x >> 3;    // 64 M-tiles
  const int bn   = (int)blockIdx.x & 7;     // 8 N-tiles
  const int lane = tid & 63, wid = tid >> 6;
  const int g = lane >> 4, l15 = lane & 15;
  const int wm = (wid >> 1) * 32, wn = (wid & 1) * 64;

  const short* Ag = A + (size_t)(bm * 64 + (tid >> 2)) * 1024 + (tid & 3) * 8;
  const short* Wg = W + (size_t)(bn * 128 + (tid >> 2)) * 1024 + (tid & 3) * 8;
  const int wofs = wid * 512;

  f32x4 acc[2][4];
#pragma unroll
  for (int i = 0; i < 2; ++i)
#pragma unroll
    for (int j = 0; j < 4; ++j) acc[i][j] = (f32x4){0.f, 0.f, 0.f, 0.f};

  // A panel (64x32 = 2048 shorts): ONE cp16 per wave at wofs tiles it exactly.
  cp16(Ag,             As[0] + wofs);
  cp16(Wg,             Bs[0] + wofs);
  cp16(Wg + 64 * 1024, Bs[0] + wofs + 2048);

  for (int r = 0; r < 32; ++r) {
    const int cur = r & 1;
    __syncthreads();
    if (r < 31) {
      const int kk = (r + 1) * 32, nxt = cur ^ 1;
      cp16(Ag + kk,             As[nxt] + wofs);
      cp16(Wg + kk,             Bs[nxt] + wofs);
      cp16(Wg + 64 * 1024 + kk, Bs[nxt] + wofs + 2048);
    }
    bf16x8 af[2], bf[4];
#pragma unroll
    for (int mt = 0; mt < 2; ++mt)
      af[mt] = *(const bf16x8*)&As[cur][(wm + mt * 16 + l15) * 32 + g * 8];
#pragma unroll
    for (int nt = 0; nt < 4; ++nt)
      bf[nt] = *(const bf16x8*)&Bs[cur][(wn + nt * 16 + l15) * 32 + g * 8];
#pragma unroll
    for (int mt = 0; mt < 2; ++mt)
#pragma unroll
      for (int nt = 0; nt < 4; ++nt)
        acc[mt][nt] = __builtin_amdgcn_mfma_f32_16x16x32_bf16(
            af[mt], bf[nt], acc[mt][nt], 0, 0, 0);
  }

  const int col0 = bn * 128 + wn;
#pragma unroll
  for (int nt = 0; nt < 4; ++nt) {
    const int col = col0 + nt * 16 + l15;
    const float bb = bias[col];
#pragma unroll
    for (int mt = 0; mt < 2; ++mt) {
      const int m0 = bm * 64 + wm + mt * 16 + g * 4;
#pragma unroll
      for (int r = 0; r < 4; ++r)
        C[(size_t)(m0 + r) * 1024 + col] = acc[mt][nt][r] + bb;
    }
  }
}

// ---------------- flash attention, static-max exp2 softmax, full keys.
// 64 q-rows per wave (4 m-tiles), Q-tile 256/block, grid 256. kf/vf reads
// amortized over 4 m-tiles. Register prefetch + dbuf K/V, ONE barrier/tile.
__global__ __launch_bounds__(256, 1) void attn_kernel(
    const short* __restrict__ Q, const short* __restrict__ K,
    const short* __restrict__ Vg, short* __restrict__ O) {
  __shared__ short Kt[2][64][72];   // [buf][key][dh]
  __shared__ short Vt[2][64][72];   // [buf][dh][key]
  __shared__ short Pt[4][64][72];   // per-wave [qrow][key]

  const int tid  = threadIdx.x;
  const int qt   = (int)blockIdx.x & 7;     // 8 q-tiles of 256
  const int bh   = (int)blockIdx.x >> 3;    // 32 (b,h)
  const int b    = bh >> 4, h = bh & 15;
  const int lane = tid & 63, wid = tid >> 6;
  const int g = lane >> 4, l15 = lane & 15;

  const int q0 = qt * 256 + wid * 64;
  bf16x8 qf[4][2];
#pragma unroll
  for (int mt = 0; mt < 4; ++mt) {
    const size_t base = (size_t)(b * 2048 + q0 + mt * 16 + l15) * 1024 + h * 64;
    qf[mt][0] = *(const bf16x8*)(Q + base + g * 8);
    qf[mt][1] = *(const bf16x8*)(Q + base + 32 + g * 8);
  }

  f32x4 o_acc[4][4];
#pragma unroll
  for (int i = 0; i < 4; ++i)
#pragma unroll
    for (int j = 0; j < 4; ++j) o_acc[i][j] = (f32x4){0.f, 0.f, 0.f, 0.f};
  float l_i[4][4];
#pragma unroll
  for (int i = 0; i < 4; ++i)
#pragma unroll
    for (int r = 0; r < 4; ++r) l_i[i][r] = 0.f;

  const int srow = tid >> 2, sch = tid & 3;
  const short* Kbase = K + (size_t)(b * 2048) * 1024 + h * 64 + sch * 8;
  const short* Vbase = Vg + (size_t)((b * 16 + h) * 64 + srow) * 2048 + sch * 8;

  // prefetch tile 0 into registers
  bf16x8 nk0, nk1, nv0, nv1;
  {
    const short* krow = Kbase + (size_t)srow * 1024;
    nk0 = *(const bf16x8*)(krow);
    nk1 = *(const bf16x8*)(krow + 32);
    nv0 = *(const bf16x8*)(Vbase);
    nv1 = *(const bf16x8*)(Vbase + 32);
  }

  for (int kt = 0; kt < 32; ++kt) {
    const int cur = kt & 1;
    *(bf16x8*)&Kt[cur][srow][sch * 8]      = nk0;
    *(bf16x8*)&Kt[cur][srow][sch * 8 + 32] = nk1;
    *(bf16x8*)&Vt[cur][srow][sch * 8]      = nv0;
    *(bf16x8*)&Vt[cur][srow][sch * 8 + 32] = nv1;
    __syncthreads();   // stores visible; prev-buf reads all done

    if (kt < 31) {
      const short* krow = Kbase + (size_t)((kt + 1) * 64 + srow) * 1024;
      nk0 = *(const bf16x8*)(krow);
      nk1 = *(const bf16x8*)(krow + 32);
      nv0 = *(const bf16x8*)(Vbase + (kt + 1) * 64);
      nv1 = *(const bf16x8*)(Vbase + (kt + 1) * 64 + 32);
    }

    // K fragments once per tile, shared across all 4 m-tiles
    bf16x8 kf[4][2];
#pragma unroll
    for (int nt = 0; nt < 4; ++nt) {
      kf[nt][0] = *(const bf16x8*)&Kt[cur][nt * 16 + l15][g * 8];
      kf[nt][1] = *(const bf16x8*)&Kt[cur][nt * 16 + l15][32 + g * 8];
    }

    // S = Q K^T per m-tile; softmax + P write immediately (frees sv regs)
#pragma unroll
    for (int mt = 0; mt < 4; ++mt) {
      f32x4 sv[4];
#pragma unroll
      for (int nt = 0; nt < 4; ++nt) {
        f32x4 z = (f32x4){0.f, 0.f, 0.f, 0.f};
        z = __builtin_amdgcn_mfma_f32_16x16x32_bf16(qf[mt][0], kf[nt][0], z, 0, 0, 0);
        z = __builtin_amdgcn_mfma_f32_16x16x32_bf16(qf[mt][1], kf[nt][1], z, 0, 0, 0);
        sv[nt] = z;
      }
#pragma unroll
      for (int r = 0; r < 4; ++r) {
        float p0 = EXP2(sv[0][r]);
        float p1 = EXP2(sv[1][r]);
        float p2 = EXP2(sv[2][r]);
        float p3 = EXP2(sv[3][r]);
        l_i[mt][r] += (p0 + p1) + (p2 + p3);
        const int pr = mt * 16 + g * 4 + r;
        Pt[wid][pr][l15]      = f2bf(p0);
        Pt[wid][pr][16 + l15] = f2bf(p1);
        Pt[wid][pr][32 + l15] = f2bf(p2);
        Pt[wid][pr][48 + l15] = f2bf(p3);
      }
    }
    // no barrier: Pt slab is wave-private; per-wave DS ops execute in order

    // O += P @ V : vf read once, shared across 4 m-tiles
    bf16x8 vf[4][2];
#pragma unroll
    for (int nt = 0; nt < 4; ++nt) {
      vf[nt][0] = *(const bf16x8*)&Vt[cur][nt * 16 + l15][g * 8];
      vf[nt][1] = *(const bf16x8*)&Vt[cur][nt * 16 + l15][32 + g * 8];
    }
#pragma unroll
    for (int mt = 0; mt < 4; ++mt) {
      bf16x8 pf0 = *(const bf16x8*)&Pt[wid][mt * 16 + l15][g * 8];
      bf16x8 pf1 = *(const bf16x8*)&Pt[wid][mt * 16 + l15][32 + g * 8];
#pragma unroll
      for (int nt = 0; nt < 4; ++nt) {
        o_acc[mt][nt] = __builtin_amdgcn_mfma_f32_16x16x32_bf16(
            pf0, vf[nt][0], o_acc[mt][nt], 0, 0, 0);
        o_acc[mt][nt] = __builtin_amdgcn_mfma_f32_16x16x32_bf16(
            pf1, vf[nt][1], o_acc[mt][nt], 0, 0, 0);
      }
    }
  }

  // epilogue: reduce l across 16 lanes, normalize, store bf16
#pragma unroll
  for (int mt = 0; mt < 4; ++mt)
#pragma unroll
    for (int r = 0; r < 4; ++r) {
      float l = l_i[mt][r];
#pragma unroll
      for (int off = 1; off < 16; off <<= 1) l += __shfl_xor(l, off, 64);
      const float inv = 1.0f / l;
      const int row = q0 + mt * 16 + g * 4 + r;
      const size_t base = (size_t)(b * 2048 + row) * 1024 + h * 64;
#pragma unroll
      for (int nt = 0; nt < 4; ++nt)
        O[base + nt * 16 + l15] = f2bf(o_acc[mt][nt][r] * inv);
    }
}

extern "C" void kernel_launch(void* const* d_in, const int* in_sizes, int n_in,
                              void* d_out, int out_size, void* d_ws, size_t ws_size,
                              hipStream_t stream) {
  (void)in_sizes; (void)n_in; (void)out_size; (void)ws_size;
  const float* q  = (const float*)d_in[0];
  const float* k  = (const float*)d_in[1];
  const float* v  = (const float*)d_in[2];
  const float* Wq = (const float*)d_in[3];
  const float* bq = (const float*)d_in[4];
  const float* Wk = (const float*)d_in[5];
  const float* bk = (const float*)d_in[6];
  const float* Wv = (const float*)d_in[7];
  const float* bv = (const float*)d_in[8];
  const float* Wo = (const float*)d_in[9];
  const float* bo = (const float*)d_in[10];
  float* out = (float*)d_out;

  short* qb  = (short*)d_ws;       // bf16 inputs
  short* kb  = qb + NE;
  short* vb  = kb + NE;
  short* Wqb = vb + NE;            // bf16 weights
  short* Wkb = Wqb + NW;
  short* Wvb = Wkb + NW;
  short* Wob = Wvb + NW;
  short* Qw  = Wob + NW;           // projected Q (pre-scaled)
  short* Kw  = Qw + NE;
  short* Vtg = Kw + NE;            // projected V [b,h,dh,s]
  short* Ob  = qb;                 // attention out (qb dead after gemm_qkv)

  cvt_kernel<<<dim3(1024, 16), 256, 0, stream>>>(q, k, v, Wq, Wk, Wv, Wo,
                                                 qb, kb, vb, Wqb, Wkb, Wvb, Wob);
  gemm_qkv<<<dim3(256, 3), 256, 0, stream>>>(qb, kb, vb, Wqb, Wkb, Wvb,
                                             bq, bk, bv, Qw, Kw, Vtg);
  attn_kernel<<<256, 256, 0, stream>>>(Qw, Kw, Vtg, Ob);
  gemm_out<<<512, 256, 0, stream>>>(Ob, Wob, bo, out);
}